// Round 3
// baseline (146.443 us; speedup 1.0000x reference)
//
#include <hip/hip_runtime.h>
#include <hip/hip_bf16.h>
#include <stdint.h>

#define M_DIM 2048
#define K_DIM 4096
#define N_DIM 4096

typedef __attribute__((ext_vector_type(8))) short short8;
typedef __attribute__((ext_vector_type(4))) float f32x4;

// RNE float -> bf16, packed pair
__device__ __forceinline__ uint32_t bf16pk(float a, float b) {
  uint32_t ua = __float_as_uint(a);
  ua = (ua + 0x7FFFu + ((ua >> 16) & 1u)) >> 16;
  uint32_t ub = __float_as_uint(b);
  ub = (ub + 0x7FFFu + ((ub >> 16) & 1u)) >> 16;
  return ua | (ub << 16);
}

__device__ __forceinline__ void glds16(const char* g, char* l) {
  __builtin_amdgcn_global_load_lds((__attribute__((address_space(1))) void*)g,
                                   (__attribute__((address_space(3))) void*)l, 16, 0, 0);
}

// ---------------------------------------------------------------------------
// Image layout (BK=32 tiles, [k-slot][row] "column-block" order):
//  xImg[mt 0..15][kt32 0..127]: 8KB tile; byte = slot*2048 + m*16
//      holds bf16 x[mt*128+m][kt32*32 + slot*8 + e], slot 0..3, m 0..127, e 0..7
//  wImg[nt8 0..15][kt32 0..127]: 16KB tile; byte = slot*4096 + n*16
//      holds bf16 W[kt32*32 + slot*8 + e][nt8*256 + n], n 0..255
// Staging is a verbatim linear copy; fragment reads are contiguous 256B
// per 16-lane group -> conflict-free, no swizzle anywhere.
// ---------------------------------------------------------------------------

// Prepass 1: x fp32 -> xImg. grid 256 = mt*16 + ktG (ktG = 8 kt32 tiles = 256 cols)
__global__ void __launch_bounds__(256) cvt_x_kernel(const float* __restrict__ x,
                                                    char* __restrict__ xImg) {
  __shared__ char lds[128 * 528];   // bf16 [128 rows][256 cols] padded to 528B/row
  const int mt = blockIdx.x >> 4, ktG = blockIdx.x & 15;
  const int tid = threadIdx.x;
  const float* xb = x + (size_t)mt * 128 * K_DIM + ktG * 256;
#pragma unroll
  for (int i = 0; i < 32; ++i) {
    int idx = i * 256 + tid;
    int row = idx >> 6, c4 = idx & 63;                  // float4 col
    float4 f = *(const float4*)(xb + (size_t)row * K_DIM + c4 * 4);
    uint2 pk;
    pk.x = bf16pk(f.x, f.y);
    pk.y = bf16pk(f.z, f.w);
    *(uint2*)(lds + row * 528 + c4 * 8) = pk;
  }
  __syncthreads();
  char* outb = xImg + (size_t)(mt * 128 + ktG * 8) * 8192;
#pragma unroll
  for (int i = 0; i < 16; ++i) {
    int o = i * 256 + tid;                              // 16B chunk id, 0..4095
    int tile = o >> 9, r = o & 511, slot = r >> 7, m = r & 127;
    uint4 v = *(const uint4*)(lds + m * 528 + tile * 64 + slot * 16);
    *(uint4*)(outb + (size_t)tile * 8192 + slot * 2048 + m * 16) = v;
  }
}

// Prepass 2: dequant int4 -> wImg. grid 512 = nt8*32 + g (one group g = 128 k)
__global__ void __launch_bounds__(256) deq_w_kernel(const uint32_t* __restrict__ qweight,
                                                    const uint32_t* __restrict__ qzeros,
                                                    const float* __restrict__ scales,
                                                    char* __restrict__ wImg) {
  const int nt8 = blockIdx.x >> 5, g = blockIdx.x & 31;
  const int t = threadIdx.x;
  const int ng = nt8 * 256 + t;
  uint32_t zq = qzeros[g * (N_DIM / 8) + (ng >> 3)];
  const int z = (int)((zq >> ((ng & 7) * 4)) & 15u) + 1;
  const float s = scales[g * N_DIM + ng];
  char* base = wImg + (size_t)nt8 * 128 * 16384;
#pragma unroll
  for (int i = 0; i < 16; ++i) {
    uint32_t q = qweight[(size_t)(g * 16 + i) * N_DIM + ng];
    float f[8];
#pragma unroll
    for (int v = 0; v < 8; ++v) {
      int w = (int)((q >> (4 * v)) & 15u);
      f[v] = (float)(w - z) * s;                        // exact int sub, cvt, mul
    }
    uint4 pk;
    pk.x = bf16pk(f[0], f[1]);
    pk.y = bf16pk(f[2], f[3]);
    pk.z = bf16pk(f[4], f[5]);
    pk.w = bf16pk(f[6], f[7]);
    int kt32 = g * 4 + (i >> 2), slot = i & 3;
    *(uint4*)(base + (size_t)kt32 * 16384 + slot * 4096 + t * 16) = pk;
  }
}

// ---------------------------------------------------------------------------
// GEMM, K-split 2: grid 512 x 256 thr (2 blocks/CU). BM=128 BN=256 BK=32,
// 4 waves 1Mx4N, per-wave 128x64 (8x4 16x16x32 frags, ratio 12 reads/32 MFMA).
// Triple-buffered LDS (3 x 24KB), ONE barrier + ONE counted vmcnt(6) per tile.
// Ledger: 6 loads/tile/thread; iter t issues t+2's loads; at iter-t wait point
// outstanding = {t,t+1} = 12 -> vmcnt(6) retires t's (in-order). Last iter
// vmcnt(0). Barrier bounds wave skew to one body; slots t%3,(t+1)%3,(t+2)%3
// distinct -> no read/write overlap.
// Output: atomicAdd (exactly 2 addends/elem -> deterministic); ks0 adds bias.
// ---------------------------------------------------------------------------
__global__ void __launch_bounds__(256, 2) gemm_kernel(const char* __restrict__ xImg,
                                                      const char* __restrict__ wImg,
                                                      const float* __restrict__ bias,
                                                      float* __restrict__ out) {
  __shared__ char lds[73728];                 // 3 buffers x (A 8KB + B 16KB)
  const int b = blockIdx.x;
  const int wg = (b & 7) * 64 + (b >> 3);     // XCD-chunked bijective swizzle (512%8==0)
  const int mb = wg >> 5, ks = (wg >> 4) & 1, nb = wg & 15;
  const int tid = threadIdx.x, lane = tid & 63, wc = tid >> 6;
  const int lr = lane & 15, lk = lane >> 4;

  f32x4 acc[8][4];
#pragma unroll
  for (int i = 0; i < 8; ++i)
#pragma unroll
    for (int j = 0; j < 4; ++j) acc[i][j] = f32x4{0.f, 0.f, 0.f, 0.f};

  const char* aT = xImg + (size_t)(mb * 128 + ks * 64) * 8192;
  const char* bT = wImg + (size_t)(nb * 128 + ks * 64) * 16384;

  int aoff[8], boff[4];
#pragma unroll
  for (int i = 0; i < 8; ++i) aoff[i] = lk * 2048 + (i * 16 + lr) * 16;
#pragma unroll
  for (int j = 0; j < 4; ++j) boff[j] = 8192 + lk * 4096 + (wc * 64 + j * 16 + lr) * 16;

#define STAGE(T, C)                                                          \
  do {                                                                       \
    char* dA = lds + (C) * 24576;                                            \
    const char* sA = aT + (size_t)(T) * 8192;                                \
    const char* sB = bT + (size_t)(T) * 16384;                               \
    glds16(sA + tid * 16, dA + tid * 16);                                    \
    glds16(sA + 4096 + tid * 16, dA + 4096 + tid * 16);                      \
    glds16(sB + tid * 16, dA + 8192 + tid * 16);                             \
    glds16(sB + 4096 + tid * 16, dA + 12288 + tid * 16);                     \
    glds16(sB + 8192 + tid * 16, dA + 16384 + tid * 16);                     \
    glds16(sB + 12288 + tid * 16, dA + 20480 + tid * 16);                    \
  } while (0)

  STAGE(0, 0);
  STAGE(1, 1);

  int c = 0;
  for (int t = 0; t < 64; ++t) {
    if (t < 63) asm volatile("s_waitcnt vmcnt(6)" ::: "memory");
    else        asm volatile("s_waitcnt vmcnt(0)" ::: "memory");
    __builtin_amdgcn_sched_barrier(0);
    __builtin_amdgcn_s_barrier();
    if (t < 62) {
      int cn = c + 2; if (cn >= 3) cn -= 3;
      STAGE(t + 2, cn);
    }
    const char* buf = lds + c * 24576;
    short8 af[8], bf[4];
#pragma unroll
    for (int i = 0; i < 8; ++i) af[i] = *(const short8*)(buf + aoff[i]);
#pragma unroll
    for (int j = 0; j < 4; ++j) bf[j] = *(const short8*)(buf + boff[j]);
    __builtin_amdgcn_s_setprio(1);
#pragma unroll
    for (int i = 0; i < 8; ++i)
#pragma unroll
      for (int j = 0; j < 4; ++j)
        acc[i][j] = __builtin_amdgcn_mfma_f32_16x16x32_bf16(af[i], bf[j], acc[i][j], 0, 0, 0);
    __builtin_amdgcn_s_setprio(0);
    c = (c == 2) ? 0 : c + 1;
  }
#undef STAGE

  // epilogue: C/D mapping col=lane&15, row=(lane>>4)*4+reg (verified R0/R1)
  const int colB = nb * 256 + wc * 64 + lr;
  const int rowB = mb * 128 + lk * 4;
#pragma unroll
  for (int j = 0; j < 4; ++j) {
    int col = colB + j * 16;
    float bj = (ks == 0) ? bias[col] : 0.f;
#pragma unroll
    for (int i = 0; i < 8; ++i) {
      int row = rowB + i * 16;
#pragma unroll
      for (int r = 0; r < 4; ++r)
        atomicAdd(&out[(size_t)(row + r) * N_DIM + col], acc[i][j][r] + bj);
    }
  }
}

// ---------------------------------------------------------------------------
// Fallback (workspace too small): correct-but-slow fp32 tiled GEMM w/ fused dequant
// ---------------------------------------------------------------------------
__global__ void fallback_kernel(const float* __restrict__ x, const uint32_t* __restrict__ qweight,
                                const uint32_t* __restrict__ qzeros, const float* __restrict__ scales,
                                const float* __restrict__ bias, float* __restrict__ out) {
  __shared__ float xs[16][17];
  __shared__ float ws[16][17];
  int tx = threadIdx.x, ty = threadIdx.y;
  int col = blockIdx.x * 16 + tx;
  int row = blockIdx.y * 16 + ty;
  float acc = 0.f;
  for (int k0 = 0; k0 < K_DIM; k0 += 16) {
    xs[ty][tx] = x[(size_t)row * K_DIM + k0 + tx];
    int k = k0 + ty;
    int g = k >> 7;
    uint32_t q = qweight[(size_t)(k >> 3) * N_DIM + col];
    int w = (int)((q >> ((k & 7) * 4)) & 15u);
    uint32_t zq = qzeros[g * (N_DIM / 8) + (col >> 3)];
    int z = (int)((zq >> ((col & 7) * 4)) & 15u) + 1;
    ws[ty][tx] = (float)(w - z) * scales[g * N_DIM + col];
    __syncthreads();
#pragma unroll
    for (int kk = 0; kk < 16; ++kk) acc += xs[ty][kk] * ws[kk][tx];
    __syncthreads();
  }
  out[(size_t)row * N_DIM + col] = acc + bias[col];
}

extern "C" void kernel_launch(void* const* d_in, const int* in_sizes, int n_in,
                              void* d_out, int out_size, void* d_ws, size_t ws_size,
                              hipStream_t stream) {
  const float* x = (const float*)d_in[0];
  const uint32_t* qweight = (const uint32_t*)d_in[1];
  const uint32_t* qzeros = (const uint32_t*)d_in[2];
  const float* scales = (const float*)d_in[3];
  // d_in[4] = g_idx (== arange(K)//128, folded into index math)
  const float* bias = (const float*)d_in[5];
  float* out = (float*)d_out;

  const size_t X_IMG_BYTES = (size_t)16 * 128 * 8192;    // 16.78 MB
  const size_t W_IMG_BYTES = (size_t)16 * 128 * 16384;   // 33.55 MB

  if (ws_size >= X_IMG_BYTES + W_IMG_BYTES) {
    char* xImg = (char*)d_ws;
    char* wImg = (char*)d_ws + X_IMG_BYTES;
    hipMemsetAsync(out, 0, (size_t)M_DIM * N_DIM * sizeof(float), stream);
    cvt_x_kernel<<<256, 256, 0, stream>>>(x, xImg);
    deq_w_kernel<<<512, 256, 0, stream>>>(qweight, qzeros, scales, wImg);
    gemm_kernel<<<512, 256, 0, stream>>>(xImg, wImg, bias, out);
  } else {
    fallback_kernel<<<dim3(N_DIM / 16, M_DIM / 16), dim3(16, 16), 0, stream>>>(
        x, qweight, qzeros, scales, bias, out);
  }
}

// Round 4
// 96.872 us; speedup vs baseline: 1.5117x; 1.5117x over previous
//
#include <hip/hip_runtime.h>
#include <hip/hip_bf16.h>
#include <stdint.h>

#define M_DIM 2048
#define K_DIM 4096
#define N_DIM 4096

typedef __attribute__((ext_vector_type(8))) short short8;
typedef __attribute__((ext_vector_type(4))) float f32x4;

// RNE float -> bf16, packed pair
__device__ __forceinline__ uint32_t bf16pk(float a, float b) {
  uint32_t ua = __float_as_uint(a);
  ua = (ua + 0x7FFFu + ((ua >> 16) & 1u)) >> 16;
  uint32_t ub = __float_as_uint(b);
  ub = (ub + 0x7FFFu + ((ub >> 16) & 1u)) >> 16;
  return ua | (ub << 16);
}

__device__ __forceinline__ void glds16(const char* g, char* l) {
  __builtin_amdgcn_global_load_lds((__attribute__((address_space(1))) void*)g,
                                   (__attribute__((address_space(3))) void*)l, 16, 0, 0);
}

// ---------------------------------------------------------------------------
// Image layout (BK=64 tiles, [k-slot][row][16B] — R2-measured 0-conflict):
//  xImg[mt 8][kt 64]: 32KB tile; byte = slot*4096 + row*16
//      holds bf16 x[mt*256+row][kt*64 + slot*8 + e], slot 0..7, row 0..255
//  wImg[nt 16][kt 64]: 32KB tile; byte = slot*4096 + col*16
//      holds bf16 W[kt*64 + slot*8 + e][nt*256 + col]
// Staging is a verbatim linear copy (glds-legal); frag reads are 4x256B
// chunks at 4KB stride (0 conflicts measured in R2).
// ---------------------------------------------------------------------------

// Prepass 1: x fp32 -> xImg. grid 512 = mt*64 + kt
__global__ void __launch_bounds__(256) cvt_x_kernel(const float* __restrict__ x,
                                                    char* __restrict__ xImg) {
  const int mt = blockIdx.x >> 6, kt = blockIdx.x & 63;
  const int tid = threadIdx.x;
  const int k8 = tid & 7, rbase = tid >> 3;   // 32 row-groups
  const float* xb = x + (size_t)mt * 256 * K_DIM + kt * 64 + k8 * 8;
  char* ob = xImg + (size_t)(mt * 64 + kt) * 32768 + k8 * 4096;
#pragma unroll
  for (int j = 0; j < 8; ++j) {
    int row = j * 32 + rbase;
    const float* src = xb + (size_t)row * K_DIM;
    float4 f0 = *(const float4*)src;
    float4 f1 = *(const float4*)(src + 4);
    uint4 pk;
    pk.x = bf16pk(f0.x, f0.y);
    pk.y = bf16pk(f0.z, f0.w);
    pk.z = bf16pk(f1.x, f1.y);
    pk.w = bf16pk(f1.z, f1.w);
    *(uint4*)(ob + row * 16) = pk;
  }
}

// Prepass 2: dequant int4 -> wImg. grid 1024 = nt*64 + kt
__global__ void __launch_bounds__(256) deq_w_kernel(const uint32_t* __restrict__ qweight,
                                                    const uint32_t* __restrict__ qzeros,
                                                    const float* __restrict__ scales,
                                                    char* __restrict__ wImg) {
  const int nt = blockIdx.x >> 6, kt = blockIdx.x & 63;
  const int t = threadIdx.x;
  const int n = nt * 256 + t;
  const int g = kt >> 1;                       // BK=64, group=128
  uint32_t zq = qzeros[g * (N_DIM / 8) + (n >> 3)];
  const int z = (int)((zq >> ((n & 7) * 4)) & 15u) + 1;
  const float s = scales[g * N_DIM + n];
  char* ob = wImg + (size_t)(nt * 64 + kt) * 32768;
#pragma unroll
  for (int slot = 0; slot < 8; ++slot) {
    uint32_t q = qweight[(size_t)(kt * 8 + slot) * N_DIM + n];
    float f[8];
#pragma unroll
    for (int v = 0; v < 8; ++v) {
      int w = (int)((q >> (4 * v)) & 15u);
      f[v] = (float)(w - z) * s;               // exact int sub, cvt, mul
    }
    uint4 pk;
    pk.x = bf16pk(f[0], f[1]);
    pk.y = bf16pk(f[2], f[3]);
    pk.z = bf16pk(f[4], f[5]);
    pk.w = bf16pk(f[6], f[7]);
    *(uint4*)(ob + slot * 4096 + t * 16) = pk;
  }
}

// ---------------------------------------------------------------------------
// GEMM: BM=BN=256, BK=64, 8 waves (2Mx4N), per-wave 128x64. K-split 2.
// grid 256 x 512 thr (1 block/CU, 8 waves). 2 LDS buffers x 64KB.
// 4 phases per K-tile, each: {1 half-tile stage (2 glds) | ds_reads | 16 MFMA}.
// Staging targets the half-tile freed >=1 phase earlier (barrier-protected).
//
// vmcnt ledger (half-tile = 2 glds; issue order per tile t, buf c=t&1, n=c^1):
//   p0 stages (t+1).A-K1 -> buf n   [t<31]
//   p1 stages (t+1).B-K1 -> buf n   [t<31]
//   p2 stages (t+2).A-K0 -> buf c   [t<30]
//   p3 stages (t+2).B-K0 -> buf c   [t<30]
// Steady state at p0/p2: exactly 6 half-tiles (12 glds) outstanding; the
// oldest 2 are this phase's operands -> s_waitcnt vmcnt(8). Issue-to-use
// window: 4-6 phases. Tail: t=31 -> vmcnt(4) at p0, vmcnt(0) at p2.
// Epilogue: ks0 -> out(+bias), ks1 -> part1 (plain stores; no atomics) when
// ws allows, else atomic fallback.
// ---------------------------------------------------------------------------
__global__ void __launch_bounds__(512, 2) gemm_kernel(const char* __restrict__ xImg,
                                                      const char* __restrict__ wImg,
                                                      const float* __restrict__ bias,
                                                      float* __restrict__ out,
                                                      float* __restrict__ part1) {
  __shared__ uint4 ldsv[8192];                 // 131072 B = 2 x 64KB
  char* lds = (char*)ldsv;
  const int tid = threadIdx.x;
  const int lane = tid & 63, wid = tid >> 6;
  const int wr = wid >> 2, wc = wid & 3;       // 2M x 4N waves
  const int lr = lane & 15, lk = lane >> 4;

  // XCD-chunked mapping: xcd = bid&7 shares an nb-pair (B set ~4MB = L2)
  const int bid = blockIdx.x;                  // 256 blocks
  const int i5 = bid >> 3;                     // 0..31
  const int nb = (bid & 7) * 2 + (i5 & 1);
  const int mb = (i5 >> 1) & 7;
  const int ks = i5 >> 4;

  f32x4 acc[8][4];
#pragma unroll
  for (int i = 0; i < 8; ++i)
#pragma unroll
    for (int j = 0; j < 4; ++j) acc[i][j] = f32x4{0.f, 0.f, 0.f, 0.f};

  const char* aT = xImg + (size_t)(mb * 64 + ks * 32) * 32768;
  const char* bT = wImg + (size_t)(nb * 64 + ks * 32) * 32768;

  int aoff[8], boff[4];
#pragma unroll
  for (int i = 0; i < 8; ++i) aoff[i] = lk * 4096 + (wr * 128 + i * 16 + lr) * 16;
#pragma unroll
  for (int j = 0; j < 4; ++j) boff[j] = 32768 + lk * 4096 + (wc * 64 + j * 16 + lr) * 16;

#define STG(src, off)                                        \
  do {                                                       \
    glds16((src) + tid * 16, lds + (off) + tid * 16);        \
    glds16((src) + 8192 + tid * 16, lds + (off) + 8192 + tid * 16); \
  } while (0)

  // prologue: stack (oldest->newest): 0.AK0, 0.BK0, 0.AK1, 0.BK1, 1.AK0, 1.BK0
  STG(aT, 0);
  STG(bT, 32768);
  STG(aT + 16384, 16384);
  STG(bT + 16384, 49152);
  STG(aT + 32768, 65536);
  STG(bT + 32768, 65536 + 32768);

#pragma unroll 2
  for (int t = 0; t < 32; ++t) {
    const int c = t & 1;
    char* bufc = lds + c * 65536;
    char* bufn = lds + (c ^ 1) * 65536;
    const char* aN1 = aT + (size_t)(t + 1) * 32768;
    const char* bN1 = bT + (size_t)(t + 1) * 32768;
    const char* aN2 = aT + (size_t)(t + 2) * 32768;
    const char* bN2 = bT + (size_t)(t + 2) * 32768;
    short8 a[8], b0, b1, b2, b3;

    // ---- p0: kk=0, cols j01 ----
    if (t == 31) asm volatile("s_waitcnt vmcnt(4)" ::: "memory");
    else         asm volatile("s_waitcnt vmcnt(8)" ::: "memory");
    __builtin_amdgcn_sched_barrier(0);
    __builtin_amdgcn_s_barrier();
    if (t < 31) STG(aN1 + 16384, (c ^ 1) * 65536 + 16384);      // (t+1).A-K1
#pragma unroll
    for (int i = 0; i < 8; ++i) a[i] = *(const short8*)(bufc + aoff[i]);
    b0 = *(const short8*)(bufc + boff[0]);
    b1 = *(const short8*)(bufc + boff[1]);
    __builtin_amdgcn_s_setprio(1);
#pragma unroll
    for (int i = 0; i < 8; ++i) {
      acc[i][0] = __builtin_amdgcn_mfma_f32_16x16x32_bf16(a[i], b0, acc[i][0], 0, 0, 0);
      acc[i][1] = __builtin_amdgcn_mfma_f32_16x16x32_bf16(a[i], b1, acc[i][1], 0, 0, 0);
    }
    __builtin_amdgcn_s_setprio(0);

    // ---- p1: kk=0, cols j23 ----
    __builtin_amdgcn_s_barrier();
    if (t < 31) STG(bN1 + 16384, (c ^ 1) * 65536 + 32768 + 16384); // (t+1).B-K1
    b2 = *(const short8*)(bufc + boff[2]);
    b3 = *(const short8*)(bufc + boff[3]);
    __builtin_amdgcn_s_setprio(1);
#pragma unroll
    for (int i = 0; i < 8; ++i) {
      acc[i][2] = __builtin_amdgcn_mfma_f32_16x16x32_bf16(a[i], b2, acc[i][2], 0, 0, 0);
      acc[i][3] = __builtin_amdgcn_mfma_f32_16x16x32_bf16(a[i], b3, acc[i][3], 0, 0, 0);
    }
    __builtin_amdgcn_s_setprio(0);

    // ---- p2: kk=1, cols j01 ----
    if (t == 31) asm volatile("s_waitcnt vmcnt(0)" ::: "memory");
    else         asm volatile("s_waitcnt vmcnt(8)" ::: "memory");
    __builtin_amdgcn_sched_barrier(0);
    __builtin_amdgcn_s_barrier();
    if (t < 30) STG(aN2, c * 65536);                             // (t+2).A-K0
#pragma unroll
    for (int i = 0; i < 8; ++i) a[i] = *(const short8*)(bufc + aoff[i] + 16384);
    b0 = *(const short8*)(bufc + boff[0] + 16384);
    b1 = *(const short8*)(bufc + boff[1] + 16384);
    __builtin_amdgcn_s_setprio(1);
#pragma unroll
    for (int i = 0; i < 8; ++i) {
      acc[i][0] = __builtin_amdgcn_mfma_f32_16x16x32_bf16(a[i], b0, acc[i][0], 0, 0, 0);
      acc[i][1] = __builtin_amdgcn_mfma_f32_16x16x32_bf16(a[i], b1, acc[i][1], 0, 0, 0);
    }
    __builtin_amdgcn_s_setprio(0);

    // ---- p3: kk=1, cols j23 ----
    __builtin_amdgcn_s_barrier();
    if (t < 30) STG(bN2, c * 65536 + 32768);                     // (t+2).B-K0
    b2 = *(const short8*)(bufc + boff[2] + 16384);
    b3 = *(const short8*)(bufc + boff[3] + 16384);
    __builtin_amdgcn_s_setprio(1);
#pragma unroll
    for (int i = 0; i < 8; ++i) {
      acc[i][2] = __builtin_amdgcn_mfma_f32_16x16x32_bf16(a[i], b2, acc[i][2], 0, 0, 0);
      acc[i][3] = __builtin_amdgcn_mfma_f32_16x16x32_bf16(a[i], b3, acc[i][3], 0, 0, 0);
    }
    __builtin_amdgcn_s_setprio(0);
  }
#undef STG

  // epilogue: C/D map col=lane&15, row=(lane>>4)*4+reg (verified R0-R2)
  const int colB = nb * 256 + wc * 64 + lr;
  const int rowB = mb * 256 + wr * 128 + lk * 4;
  if (part1 != nullptr) {
    float* dst = ks ? part1 : out;
#pragma unroll
    for (int j = 0; j < 4; ++j) {
      int col = colB + j * 16;
      float bj = (ks == 0) ? bias[col] : 0.f;
#pragma unroll
      for (int i = 0; i < 8; ++i) {
        int row = rowB + i * 16;
#pragma unroll
        for (int r = 0; r < 4; ++r)
          dst[(size_t)(row + r) * N_DIM + col] = acc[i][j][r] + bj;
      }
    }
  } else {
#pragma unroll
    for (int j = 0; j < 4; ++j) {
      int col = colB + j * 16;
      float bj = (ks == 0) ? bias[col] : 0.f;
#pragma unroll
      for (int i = 0; i < 8; ++i) {
        int row = rowB + i * 16;
#pragma unroll
        for (int r = 0; r < 4; ++r)
          atomicAdd(&out[(size_t)(row + r) * N_DIM + col], acc[i][j][r] + bj);
      }
    }
  }
}

// out += part1 (8192 blocks x 256 thr x float4 = 8.39M floats)
__global__ void __launch_bounds__(256) reduce_kernel(float* __restrict__ out,
                                                     const float* __restrict__ part1) {
  int i = blockIdx.x * 256 + threadIdx.x;
  float4 o = ((const float4*)out)[i];
  float4 p = ((const float4*)part1)[i];
  o.x += p.x; o.y += p.y; o.z += p.z; o.w += p.w;
  ((float4*)out)[i] = o;
}

// ---------------------------------------------------------------------------
// Fallback (workspace too small): correct-but-slow fp32 tiled GEMM w/ fused dequant
// ---------------------------------------------------------------------------
__global__ void fallback_kernel(const float* __restrict__ x, const uint32_t* __restrict__ qweight,
                                const uint32_t* __restrict__ qzeros, const float* __restrict__ scales,
                                const float* __restrict__ bias, float* __restrict__ out) {
  __shared__ float xs[16][17];
  __shared__ float ws[16][17];
  int tx = threadIdx.x, ty = threadIdx.y;
  int col = blockIdx.x * 16 + tx;
  int row = blockIdx.y * 16 + ty;
  float acc = 0.f;
  for (int k0 = 0; k0 < K_DIM; k0 += 16) {
    xs[ty][tx] = x[(size_t)row * K_DIM + k0 + tx];
    int k = k0 + ty;
    int g = k >> 7;
    uint32_t q = qweight[(size_t)(k >> 3) * N_DIM + col];
    int w = (int)((q >> ((k & 7) * 4)) & 15u);
    uint32_t zq = qzeros[g * (N_DIM / 8) + (col >> 3)];
    int z = (int)((zq >> ((col & 7) * 4)) & 15u) + 1;
    ws[ty][tx] = (float)(w - z) * scales[g * N_DIM + col];
    __syncthreads();
#pragma unroll
    for (int kk = 0; kk < 16; ++kk) acc += xs[ty][kk] * ws[kk][tx];
    __syncthreads();
  }
  out[(size_t)row * N_DIM + col] = acc + bias[col];
}

extern "C" void kernel_launch(void* const* d_in, const int* in_sizes, int n_in,
                              void* d_out, int out_size, void* d_ws, size_t ws_size,
                              hipStream_t stream) {
  const float* x = (const float*)d_in[0];
  const uint32_t* qweight = (const uint32_t*)d_in[1];
  const uint32_t* qzeros = (const uint32_t*)d_in[2];
  const float* scales = (const float*)d_in[3];
  // d_in[4] = g_idx (== arange(K)//128, folded into index math)
  const float* bias = (const float*)d_in[5];
  float* out = (float*)d_out;

  const size_t X_IMG = (size_t)8 * 64 * 32768;    // 16.78 MB
  const size_t W_IMG = (size_t)16 * 64 * 32768;   // 33.55 MB
  const size_t PART = (size_t)M_DIM * N_DIM * 4;  // 33.55 MB

  if (ws_size >= X_IMG + W_IMG + PART) {
    char* xImg = (char*)d_ws;
    char* wImg = (char*)d_ws + X_IMG;
    float* part1 = (float*)((char*)d_ws + X_IMG + W_IMG);
    cvt_x_kernel<<<512, 256, 0, stream>>>(x, xImg);
    deq_w_kernel<<<1024, 256, 0, stream>>>(qweight, qzeros, scales, wImg);
    gemm_kernel<<<256, 512, 0, stream>>>(xImg, wImg, bias, out, part1);
    reduce_kernel<<<8192, 256, 0, stream>>>(out, part1);
  } else if (ws_size >= X_IMG + W_IMG) {
    char* xImg = (char*)d_ws;
    char* wImg = (char*)d_ws + X_IMG;
    hipMemsetAsync(out, 0, (size_t)M_DIM * N_DIM * sizeof(float), stream);
    cvt_x_kernel<<<512, 256, 0, stream>>>(x, xImg);
    deq_w_kernel<<<1024, 256, 0, stream>>>(qweight, qzeros, scales, wImg);
    gemm_kernel<<<256, 512, 0, stream>>>(xImg, wImg, bias, out, nullptr);
  } else {
    fallback_kernel<<<dim3(N_DIM / 16, M_DIM / 16), dim3(16, 16), 0, stream>>>(
        x, qweight, qzeros, scales, bias, out);
  }
}